// Round 2
// baseline (388.565 us; speedup 1.0000x reference)
//
#include <hip/hip_runtime.h>

#define NN 50000
#define TT 12
#define QQ 3
#define HH 64
#define KK 32
#define TQ 36   // T*Q
#define NLEV 4

// ---------------------------------------------------------------------------
// Projection: out[r][q] = sum_h gnn[r][h] * w[h][q] + b[q],  r in [0, N*T)
// One wave processes 4 rows per iteration: lane loads float4 (coalesced 1KiB
// per wave), 16-lane groups own one row each, shuffle-tree reduce.
// ---------------------------------------------------------------------------
__global__ __launch_bounds__(256) void proj_kernel(
    const float* __restrict__ gnn, const float* __restrict__ w,
    const float* __restrict__ b, float* __restrict__ out, int nrows)
{
    const int lane = threadIdx.x & 63;
    const int sub  = lane & 15;          // position within 16-lane row-group
    const int h0   = sub * 4;            // this lane's 4 h-indices

    // preload weights for my 4 h values (L1-resident, once per wave)
    float wreg[4][3];
#pragma unroll
    for (int j = 0; j < 4; ++j)
#pragma unroll
        for (int q = 0; q < 3; ++q)
            wreg[j][q] = w[(h0 + j) * 3 + q];
    const float b0 = b[0], b1 = b[1], b2 = b[2];

    const int gwave  = (blockIdx.x * blockDim.x + threadIdx.x) >> 6;
    const int nwaves = (gridDim.x * blockDim.x) >> 6;
    const int nquads = nrows >> 2;       // rows processed 4 at a time

    for (int quad = gwave; quad < nquads; quad += nwaves) {
        const float4 g = *reinterpret_cast<const float4*>(gnn + (size_t)quad * 256 + lane * 4);
        float a0 = g.x * wreg[0][0] + g.y * wreg[1][0] + g.z * wreg[2][0] + g.w * wreg[3][0];
        float a1 = g.x * wreg[0][1] + g.y * wreg[1][1] + g.z * wreg[2][1] + g.w * wreg[3][1];
        float a2 = g.x * wreg[0][2] + g.y * wreg[1][2] + g.z * wreg[2][2] + g.w * wreg[3][2];
#pragma unroll
        for (int off = 8; off > 0; off >>= 1) {
            a0 += __shfl_down(a0, off);
            a1 += __shfl_down(a1, off);
            a2 += __shfl_down(a2, off);
        }
        if (sub == 0) {
            const int row = quad * 4 + (lane >> 4);
            out[row * 3 + 0] = a0 + b0;
            out[row * 3 + 1] = a1 + b1;
            out[row * 3 + 2] = a2 + b2;
        }
    }
}

// ---------------------------------------------------------------------------
// Build per-level node lists (order irrelevant — values are order-independent)
// ---------------------------------------------------------------------------
__global__ __launch_bounds__(256) void compact_kernel(
    const int* __restrict__ lvl, int* __restrict__ counts,
    int* __restrict__ lists)
{
    const int i = blockIdx.x * blockDim.x + threadIdx.x;
    if (i >= NN) return;
    const int l = lvl[i];
    const int pos = atomicAdd(&counts[l], 1);
    lists[l * NN + pos] = i;
}

// ---------------------------------------------------------------------------
// Aggregate one level: for nodes at `level`, tmp = (sum_k out[key]*sc[key]) / sc[node]
// Reads the pre-level `out` state; writes compacted tmp (no in-place races).
// Thread = (list-index, tq); 36 consecutive threads share a node -> coalesced
// writes; gathers served by L2/L3 (out state = 7.2 MB).
// ---------------------------------------------------------------------------
__global__ __launch_bounds__(256) void agg_kernel(
    const float* __restrict__ out, const float* __restrict__ scaler,
    const int* __restrict__ keybom, const int* __restrict__ lists,
    const int* __restrict__ counts, float* __restrict__ tmp, int level)
{
    const int idx = blockIdx.x * blockDim.x + threadIdx.x;
    const int li  = idx / TQ;
    const int tq  = idx - li * TQ;
    if (li >= counts[level]) return;
    const int node = lists[level * NN + li];
    const int t = tq / QQ;

    const int* kb = keybom + (size_t)node * KK;
    float acc = 0.0f;
#pragma unroll 4
    for (int k = 0; k < KK; ++k) {
        const int key = kb[k];
        if (key >= 0) {
            acc += out[(size_t)key * TQ + tq] * scaler[key * TT + t];
        }
    }
    tmp[(size_t)li * TQ + tq] = acc / scaler[node * TT + t];
}

// ---------------------------------------------------------------------------
// Scatter the level's results back into out.
// ---------------------------------------------------------------------------
__global__ __launch_bounds__(256) void scatter_kernel(
    const int* __restrict__ lists, const int* __restrict__ counts,
    const float* __restrict__ tmp, float* __restrict__ out, int level)
{
    const int idx = blockIdx.x * blockDim.x + threadIdx.x;
    const int li  = idx / TQ;
    const int tq  = idx - li * TQ;
    if (li >= counts[level]) return;
    const int node = lists[level * NN + li];
    out[(size_t)node * TQ + tq] = tmp[(size_t)li * TQ + tq];
}

extern "C" void kernel_launch(void* const* d_in, const int* in_sizes, int n_in,
                              void* d_out, int out_size, void* d_ws, size_t ws_size,
                              hipStream_t stream)
{
    const float* gnn    = (const float*)d_in[0];
    const float* w      = (const float*)d_in[1];
    const float* b      = (const float*)d_in[2];
    const float* scaler = (const float*)d_in[3];
    const int*   keybom = (const int*)d_in[4];   // harness passes integers as int32
    const int*   lvl    = (const int*)d_in[5];   // (N,1) int32
    float* out = (float*)d_out;

    char* ws = (char*)d_ws;
    int*   counts = (int*)ws;                                  // 4 ints (16 B)
    int*   lists  = (int*)(ws + 16);                           // 4*NN ints
    float* tmp    = (float*)(ws + 16 + (size_t)4 * NN * 4);    // NN*TQ floats

    hipMemsetAsync(counts, 0, 16, stream);

    const int nrows = NN * TT;
    proj_kernel<<<2048, 256, 0, stream>>>(gnn, w, b, out, nrows);
    compact_kernel<<<(NN + 255) / 256, 256, 0, stream>>>(lvl, counts, lists);

    const int blocks = (NN * TQ + 255) / 256;
    for (int level = 1; level < NLEV; ++level) {
        agg_kernel<<<blocks, 256, 0, stream>>>(out, scaler, keybom, lists, counts, tmp, level);
        scatter_kernel<<<blocks, 256, 0, stream>>>(lists, counts, tmp, out, level);
    }
}

// Round 3
// 153.730 us; speedup vs baseline: 2.5276x; 2.5276x over previous
//
#include <hip/hip_runtime.h>

#define NN 50000
#define TT 12
#define QQ 3
#define HH 64
#define KK 32
#define TQ 36   // T*Q
#define NLEV 4

// ---------------------------------------------------------------------------
// Projection: out[r][q] = sum_h gnn[r][h] * w[h][q] + b[q],  r in [0, N*T)
// One wave processes 4 rows per iteration: lane loads float4 (coalesced 1KiB
// per wave), 16-lane groups own one row each, shuffle-tree reduce.
// ---------------------------------------------------------------------------
__global__ __launch_bounds__(256) void proj_kernel(
    const float* __restrict__ gnn, const float* __restrict__ w,
    const float* __restrict__ b, float* __restrict__ out, int nrows)
{
    const int lane = threadIdx.x & 63;
    const int sub  = lane & 15;          // position within 16-lane row-group
    const int h0   = sub * 4;            // this lane's 4 h-indices

    float wreg[4][3];
#pragma unroll
    for (int j = 0; j < 4; ++j)
#pragma unroll
        for (int q = 0; q < 3; ++q)
            wreg[j][q] = w[(h0 + j) * 3 + q];
    const float b0 = b[0], b1 = b[1], b2 = b[2];

    const int gwave  = (blockIdx.x * blockDim.x + threadIdx.x) >> 6;
    const int nwaves = (gridDim.x * blockDim.x) >> 6;
    const int nquads = nrows >> 2;

    for (int quad = gwave; quad < nquads; quad += nwaves) {
        const float4 g = *reinterpret_cast<const float4*>(gnn + (size_t)quad * 256 + lane * 4);
        float a0 = g.x * wreg[0][0] + g.y * wreg[1][0] + g.z * wreg[2][0] + g.w * wreg[3][0];
        float a1 = g.x * wreg[0][1] + g.y * wreg[1][1] + g.z * wreg[2][1] + g.w * wreg[3][1];
        float a2 = g.x * wreg[0][2] + g.y * wreg[1][2] + g.z * wreg[2][2] + g.w * wreg[3][2];
#pragma unroll
        for (int off = 8; off > 0; off >>= 1) {
            a0 += __shfl_down(a0, off);
            a1 += __shfl_down(a1, off);
            a2 += __shfl_down(a2, off);
        }
        if (sub == 0) {
            const int row = quad * 4 + (lane >> 4);
            out[row * 3 + 0] = a0 + b0;
            out[row * 3 + 1] = a1 + b1;
            out[row * 3 + 2] = a2 + b2;
        }
    }
}

// ---------------------------------------------------------------------------
// Build per-level node lists. Wave-aggregated atomics: one atomicAdd per
// (wave, level-present) instead of per thread — kills the 270us contention
// serialization seen in R2 (50k atomics on 4 addresses).
// ---------------------------------------------------------------------------
__global__ __launch_bounds__(256) void compact_kernel(
    const int* __restrict__ lvl, int* __restrict__ counts,
    int* __restrict__ lists)
{
    const int i    = blockIdx.x * blockDim.x + threadIdx.x;
    const int lane = threadIdx.x & 63;
    const int l    = (i < NN) ? lvl[i] : -1;
    const unsigned long long below = (lane == 63) ? ~0ull >> 1
                                   : ((1ull << lane) - 1);
#pragma unroll
    for (int lev = 0; lev < NLEV; ++lev) {
        const unsigned long long m = __ballot(l == lev);
        if (m == 0ull) continue;
        const int leader = __ffsll((long long)m) - 1;
        int base = 0;
        if (lane == leader) base = atomicAdd(&counts[lev], __popcll(m));
        base = __shfl(base, leader);           // executed by ALL lanes
        if (l == lev) {
            const int before = __popcll(m & below);
            lists[lev * NN + base + before] = i;
        }
    }
}

// ---------------------------------------------------------------------------
// Aggregate one level: tmp = (sum_k out[key]*sc[key]) / sc[node]
// Reads pre-level `out`; writes compacted tmp (no in-place races).
// ---------------------------------------------------------------------------
__global__ __launch_bounds__(256) void agg_kernel(
    const float* __restrict__ out, const float* __restrict__ scaler,
    const int* __restrict__ keybom, const int* __restrict__ lists,
    const int* __restrict__ counts, float* __restrict__ tmp, int level)
{
    const int idx = blockIdx.x * blockDim.x + threadIdx.x;
    const int li  = idx / TQ;
    const int tq  = idx - li * TQ;
    if (li >= counts[level]) return;
    const int node = lists[level * NN + li];
    const int t = tq / QQ;

    const int* kb = keybom + (size_t)node * KK;
    float acc = 0.0f;
#pragma unroll 4
    for (int k = 0; k < KK; ++k) {
        const int key = kb[k];
        if (key >= 0) {
            acc += out[(size_t)key * TQ + tq] * scaler[key * TT + t];
        }
    }
    tmp[(size_t)li * TQ + tq] = acc / scaler[node * TT + t];
}

// ---------------------------------------------------------------------------
// Scatter the level's results back into out.
// ---------------------------------------------------------------------------
__global__ __launch_bounds__(256) void scatter_kernel(
    const int* __restrict__ lists, const int* __restrict__ counts,
    const float* __restrict__ tmp, float* __restrict__ out, int level)
{
    const int idx = blockIdx.x * blockDim.x + threadIdx.x;
    const int li  = idx / TQ;
    const int tq  = idx - li * TQ;
    if (li >= counts[level]) return;
    const int node = lists[level * NN + li];
    out[(size_t)node * TQ + tq] = tmp[(size_t)li * TQ + tq];
}

extern "C" void kernel_launch(void* const* d_in, const int* in_sizes, int n_in,
                              void* d_out, int out_size, void* d_ws, size_t ws_size,
                              hipStream_t stream)
{
    const float* gnn    = (const float*)d_in[0];
    const float* w      = (const float*)d_in[1];
    const float* b      = (const float*)d_in[2];
    const float* scaler = (const float*)d_in[3];
    const int*   keybom = (const int*)d_in[4];
    const int*   lvl    = (const int*)d_in[5];
    float* out = (float*)d_out;

    char* ws = (char*)d_ws;
    int*   counts = (int*)ws;                                  // 4 ints
    int*   lists  = (int*)(ws + 16);                           // 4*NN ints
    float* tmp    = (float*)(ws + 16 + (size_t)4 * NN * 4);    // NN*TQ floats

    hipMemsetAsync(counts, 0, 16, stream);

    const int nrows = NN * TT;
    proj_kernel<<<2048, 256, 0, stream>>>(gnn, w, b, out, nrows);
    compact_kernel<<<(NN + 255) / 256, 256, 0, stream>>>(lvl, counts, lists);

    const int blocks = (NN * TQ + 255) / 256;
    for (int level = 1; level < NLEV; ++level) {
        agg_kernel<<<blocks, 256, 0, stream>>>(out, scaler, keybom, lists, counts, tmp, level);
        scatter_kernel<<<blocks, 256, 0, stream>>>(lists, counts, tmp, out, level);
    }
}